// Round 7
// baseline (701.193 us; speedup 1.0000x reference)
//
#include <hip/hip_runtime.h>
#include <math.h>

#define BATCH 256
#define TX 512
#define TS 512
#define DH 128

__device__ __forceinline__ float sigf(float x) {
    return __builtin_amdgcn_rcpf(1.0f + __expf(-x));
}
__device__ __forceinline__ float tanhfast(float x) {
    return fmaf(-2.0f, __builtin_amdgcn_rcpf(__expf(2.0f * x) + 1.0f), 1.0f);
}
template<int CTRL>
__device__ __forceinline__ float dpp_f32(float x) {
    return __int_as_float(__builtin_amdgcn_update_dpp(
        0, __float_as_int(x), CTRL, 0xF, 0xF, true));
}
__device__ __forceinline__ float swz_xor4(float x) {
    // ds_swizzle BitMode: xor_mask=4 -> offset (4<<10)|0x1F = 0x101F
    return __int_as_float(__builtin_amdgcn_ds_swizzle(__float_as_int(x), 0x101F));
}
#define DPP_XOR1 0xB1  // quad_perm [1,0,3,2]
#define DPP_XOR2 0x4E  // quad_perm [2,3,0,1]
#define DPP_BC0  0x00
#define DPP_BC1  0x55
#define DPP_BC2  0xAA

// ---------------- encoder: LSTM H=3 over x[B,512,8], 4 lanes per batch elem ----
__global__ __launch_bounds__(64) void enc_kernel(
    const float* __restrict__ x, const float* __restrict__ h0, const float* __restrict__ c0,
    const float* __restrict__ We_ih, const float* __restrict__ We_hh,
    const float* __restrict__ be_ih, const float* __restrict__ be_hh,
    const float* __restrict__ Wfc_e, const float* __restrict__ bfc_e,
    float* __restrict__ out_z)
{
    const int gt = blockIdx.x * 64 + threadIdx.x;
    const int b  = gt >> 2;
    const int k  = gt & 3;
    const int kk = (k < 3) ? k : 0;

    float wx[4][8], wh[4][3], bg[4];
    #pragma unroll
    for (int g = 0; g < 4; ++g) {
        const int row = g * 3 + kk;
        #pragma unroll
        for (int m = 0; m < 8; ++m) wx[g][m] = We_ih[row * 8 + m];
        #pragma unroll
        for (int n = 0; n < 3; ++n) wh[g][n] = We_hh[row * 3 + n];
        bg[g] = be_ih[row] + be_hh[row];
    }

    float hv0 = h0[b * 3 + 0], hv1 = h0[b * 3 + 1], hv2 = h0[b * 3 + 2];
    float c = c0[b * 3 + kk];

    const float* xb = x + (size_t)b * TX * 8;
    float4 x0 = *(const float4*)(xb);
    float4 x1 = *(const float4*)(xb + 4);

    for (int t = 0; t < TX; ++t) {
        const float* xn = xb + (size_t)((t + 1 < TX) ? t + 1 : t) * 8;
        const float4 n0 = *(const float4*)(xn);
        const float4 n1 = *(const float4*)(xn + 4);

        float acc[4];
        #pragma unroll
        for (int g = 0; g < 4; ++g) {
            float a = bg[g];
            a = fmaf(wx[g][0], x0.x, a);
            a = fmaf(wx[g][1], x0.y, a);
            a = fmaf(wx[g][2], x0.z, a);
            a = fmaf(wx[g][3], x0.w, a);
            a = fmaf(wx[g][4], x1.x, a);
            a = fmaf(wx[g][5], x1.y, a);
            a = fmaf(wx[g][6], x1.z, a);
            a = fmaf(wx[g][7], x1.w, a);
            a = fmaf(wh[g][0], hv0, a);
            a = fmaf(wh[g][1], hv1, a);
            a = fmaf(wh[g][2], hv2, a);
            acc[g] = a;
        }
        const float ig = sigf(acc[0]);
        const float fg = sigf(acc[1]);
        const float gg = tanhfast(acc[2]);
        const float og = sigf(acc[3]);
        c = fmaf(fg, c, ig * gg);
        const float hk = og * tanhfast(c);
        hv0 = dpp_f32<DPP_BC0>(hk);
        hv1 = dpp_f32<DPP_BC1>(hk);
        hv2 = dpp_f32<DPP_BC2>(hk);
        x0 = n0; x1 = n1;
    }

    if (k == 0) {
        float zz = bfc_e[0];
        zz = fmaf(hv0, Wfc_e[0], zz);
        zz = fmaf(hv1, Wfc_e[1], zz);
        zz = fmaf(hv2, Wfc_e[2], zz);
        out_z[b] = zz;
    }
}

// ---------------- decoder: LSTM H=128, 8-way K-split, swizzle+DPP reduction ---
// 1024 threads: thread (j = tid>>3, q = tid&7) computes all 4 gate rows for
// h-col j over k in [16q, 16q+16).  w = 4x4 float4 = 64 VGPR -> fits the
// 128-VGPR cap the backend enforces for whole-WG residency (R5/R6: 512-thr
// design needed 128 w-floats -> spilled 27 MB scratch).
// traj_hat is fused into the prologue (same s rows, same WG).
__global__ __launch_bounds__(1024) void dec_kernel(
    const float* __restrict__ s, const float* __restrict__ z,
    const float* __restrict__ Wd_ih, const float* __restrict__ Wd_hh,
    const float* __restrict__ bd_ih, const float* __restrict__ bd_hh,
    const float* __restrict__ Wfc_d, const float* __restrict__ bfc_d,
    float* __restrict__ out_traj, float* __restrict__ out_h)
{
    // h double-buffered; 8 chunks of 16 floats at stride 20:
    // chunk bases {0,20,40,..,140} mod 32 = {0,20,8,28,16,4,24,12} -> the 8
    // ds_read_b128 of one instruction cover all 32 banks exactly once.
    __shared__ __align__(16) float hbuf[2][160];

    const int b   = blockIdx.x;
    const int tid = threadIdx.x;
    const int j   = tid >> 3;    // h-col 0..127
    const int q   = tid & 7;     // K-eighth

    // ---- fused traj_hat: thread (t = tid>>1, comp = tid&1) ----
    {
        const int t = tid >> 1, comp = tid & 1;
        const float* st = s + ((size_t)b * TS + t) * 6;
        const float2 sa = *(const float2*)(st);
        const float2 sbb = *(const float2*)(st + 2);
        const float2 sc = *(const float2*)(st + 4);
        const float* wr = Wfc_d + comp * 6;
        float o = bfc_d[comp];
        o = fmaf(sa.x,  wr[0], o); o = fmaf(sa.y,  wr[1], o);
        o = fmaf(sbb.x, wr[2], o); o = fmaf(sbb.y, wr[3], o);
        o = fmaf(sc.x,  wr[4], o); o = fmaf(sc.y,  wr[5], o);
        out_traj[((size_t)b * TS + t) * 2 + comp] = o;
    }

    // Whh K-slices for the 4 gates of col j: rows g*128+j, cols [16q, 16q+16)
    float4 w[4][4];
    #pragma unroll
    for (int g = 0; g < 4; ++g) {
        const float* wp = Wd_hh + (size_t)(g * DH + j) * DH + q * 16;
        #pragma unroll
        for (int cc = 0; cc < 4; ++cc) w[g][cc] = *(const float4*)(wp + cc * 4);
    }
    // x-part: lane q (q<4) owns gate q's s-dot; lanes 4..7 duplicate gate q-4
    const int g0 = q & 3;
    const float* wi = Wd_ih + (size_t)(g0 * DH + j) * 7;
    const float wx0 = wi[0], wx1 = wi[1], wx2 = wi[2];
    const float wx3 = wi[3], wx4 = wi[4], wx5 = wi[5];
    const float gb  = bd_ih[g0 * DH + j] + bd_hh[g0 * DH + j] + z[b] * wi[6];

    if (tid < 160) hbuf[0][tid] = 0.0f;
    float c = 0.0f;
    float hn = 0.0f;
    __syncthreads();

    const float* sb = s + (size_t)b * TS * 6;
    float2 sA = *(const float2*)(sb);
    float2 sB = *(const float2*)(sb + 2);
    float2 sC = *(const float2*)(sb + 4);

    const int rbase = q * 20;                      // this thread's K-chunk
    const int wpos  = (j >> 4) * 20 + (j & 15);    // h[j]'s slot

    for (int t = 0; t < TS; ++t) {
        const float* sn = sb + (size_t)((t + 1 < TS) ? t + 1 : t) * 6;
        const float2 nA = *(const float2*)(sn);
        const float2 nB = *(const float2*)(sn + 2);
        const float2 nC = *(const float2*)(sn + 4);

        // h chunk: 4 x ds_read_b128, conflict-free by bank layout above
        const float4* hb = (const float4*)(&hbuf[t & 1][rbase]);
        float4 h[4];
        #pragma unroll
        for (int cc = 0; cc < 4; ++cc) h[cc] = hb[cc];

        // s-dot for gate g0 (folded once: only lanes q<4)
        float sdot = gb;
        sdot = fmaf(wx0, sA.x, sdot);
        sdot = fmaf(wx1, sA.y, sdot);
        sdot = fmaf(wx2, sB.x, sdot);
        sdot = fmaf(wx3, sB.y, sdot);
        sdot = fmaf(wx4, sC.x, sdot);
        sdot = fmaf(wx5, sC.y, sdot);

        float acc[4];
        #pragma unroll
        for (int g = 0; g < 4; ++g) {
            float p0 = (g == q) ? sdot : 0.0f;   // true only for q<4, g==q
            float p1 = 0.0f, p2 = 0.0f, p3 = 0.0f;
            #pragma unroll
            for (int cc = 0; cc < 4; ++cc) {
                p0 = fmaf(w[g][cc].x, h[cc].x, p0);
                p1 = fmaf(w[g][cc].y, h[cc].y, p1);
                p2 = fmaf(w[g][cc].z, h[cc].z, p2);
                p3 = fmaf(w[g][cc].w, h[cc].w, p3);
            }
            acc[g] = (p0 + p1) + (p2 + p3);
        }

        // 8-lane butterfly: xor^4 (ds_swizzle) then xor^2, xor^1 (DPP)
        #pragma unroll
        for (int g = 0; g < 4; ++g) {
            float v = acc[g];
            v += swz_xor4(v);
            v += dpp_f32<DPP_XOR2>(v);
            v += dpp_f32<DPP_XOR1>(v);
            acc[g] = v;
        }

        const float ig = sigf(acc[0]);
        const float fg = sigf(acc[1]);
        const float gg = tanhfast(acc[2]);
        const float og = sigf(acc[3]);
        c  = fmaf(fg, c, ig * gg);
        hn = og * tanhfast(c);

        if (q == 0) hbuf[(t + 1) & 1][wpos] = hn;
        __syncthreads();

        sA = nA; sB = nB; sC = nC;
    }

    if (q == 0) out_h[(size_t)b * DH + j] = hn;
}

extern "C" void kernel_launch(void* const* d_in, const int* in_sizes, int n_in,
                              void* d_out, int out_size, void* d_ws, size_t ws_size,
                              hipStream_t stream) {
    const float* x      = (const float*)d_in[0];
    const float* s      = (const float*)d_in[1];
    const float* h0     = (const float*)d_in[2];
    const float* c0     = (const float*)d_in[3];
    const float* We_ih  = (const float*)d_in[4];
    const float* We_hh  = (const float*)d_in[5];
    const float* be_ih  = (const float*)d_in[6];
    const float* be_hh  = (const float*)d_in[7];
    const float* Wfc_e  = (const float*)d_in[8];
    const float* bfc_e  = (const float*)d_in[9];
    const float* Wd_ih  = (const float*)d_in[10];
    const float* Wd_hh  = (const float*)d_in[11];
    const float* bd_ih  = (const float*)d_in[12];
    const float* bd_hh  = (const float*)d_in[13];
    const float* Wfc_d  = (const float*)d_in[14];
    const float* bfc_d  = (const float*)d_in[15];

    float* out      = (float*)d_out;
    float* out_z    = out;                           // [256]
    float* out_traj = out + BATCH;                   // [256*512*2]
    float* out_h    = out + BATCH + BATCH * TS * 2;  // [256*128]

    enc_kernel<<<16, 64, 0, stream>>>(x, h0, c0, We_ih, We_hh, be_ih, be_hh,
                                      Wfc_e, bfc_e, out_z);
    dec_kernel<<<BATCH, 1024, 0, stream>>>(s, out_z, Wd_ih, Wd_hh, bd_ih, bd_hh,
                                           Wfc_d, bfc_d, out_traj, out_h);
}

// Round 9
// 507.831 us; speedup vs baseline: 1.3808x; 1.3808x over previous
//
#include <hip/hip_runtime.h>
#include <math.h>

#define BATCH 256
#define TX 512
#define TS 512
#define DH 128

typedef _Float16 h2 __attribute__((ext_vector_type(2)));

__device__ __forceinline__ float sigf(float x) {
    return __builtin_amdgcn_rcpf(1.0f + __expf(-x));
}
__device__ __forceinline__ float tanhfast(float x) {
    return fmaf(-2.0f, __builtin_amdgcn_rcpf(__expf(2.0f * x) + 1.0f), 1.0f);
}
template<int CTRL>
__device__ __forceinline__ float dpp_f32(float x) {
    return __int_as_float(__builtin_amdgcn_update_dpp(
        0, __float_as_int(x), CTRL, 0xF, 0xF, true));
}
#define DPP_XOR1 0xB1  // quad_perm [1,0,3,2]
#define DPP_XOR2 0x4E  // quad_perm [2,3,0,1]
#define DPP_BC0  0x00
#define DPP_BC1  0x55
#define DPP_BC2  0xAA

// ---- enc_pre: x-part of encoder gates, fully parallel ------------------------
// pre[b][t][kk*4+g] = (be_ih+be_hh)[g*3+kk] + dot(We_ih[g*3+kk], x[b][t])
__global__ __launch_bounds__(512) void enc_pre_kernel(
    const float* __restrict__ x,
    const float* __restrict__ We_ih, const float* __restrict__ be_ih,
    const float* __restrict__ be_hh, float* __restrict__ pre)
{
    const int b = blockIdx.x, t = threadIdx.x;
    const float* xp = x + ((size_t)b * TX + t) * 8;
    const float4 x0 = *(const float4*)(xp);
    const float4 x1 = *(const float4*)(xp + 4);

    float o[12];
    #pragma unroll
    for (int g = 0; g < 4; ++g) {
        #pragma unroll
        for (int kk = 0; kk < 3; ++kk) {
            const int row = g * 3 + kk;
            const float* wr = We_ih + row * 8;
            float d = be_ih[row] + be_hh[row];
            d = fmaf(wr[0], x0.x, d); d = fmaf(wr[1], x0.y, d);
            d = fmaf(wr[2], x0.z, d); d = fmaf(wr[3], x0.w, d);
            d = fmaf(wr[4], x1.x, d); d = fmaf(wr[5], x1.y, d);
            d = fmaf(wr[6], x1.z, d); d = fmaf(wr[7], x1.w, d);
            o[kk * 4 + g] = d;
        }
    }
    float* op = pre + ((size_t)b * TX + t) * 12;
    *(float4*)(op)     = make_float4(o[0], o[1], o[2],  o[3]);
    *(float4*)(op + 4) = make_float4(o[4], o[5], o[6],  o[7]);
    *(float4*)(op + 8) = make_float4(o[8], o[9], o[10], o[11]);
}

// ---- encoder serial: only the h-recurrence (x-part precomputed) --------------
__global__ __launch_bounds__(64) void enc_kernel(
    const float* __restrict__ pre, const float* __restrict__ h0,
    const float* __restrict__ c0, const float* __restrict__ We_hh,
    const float* __restrict__ Wfc_e, const float* __restrict__ bfc_e,
    float* __restrict__ out_z)
{
    const int gt = blockIdx.x * 64 + threadIdx.x;
    const int b  = gt >> 2;
    const int k  = gt & 3;
    const int kk = (k < 3) ? k : 0;

    float wh[4][3];
    #pragma unroll
    for (int g = 0; g < 4; ++g) {
        const int row = g * 3 + kk;
        #pragma unroll
        for (int n = 0; n < 3; ++n) wh[g][n] = We_hh[row * 3 + n];
    }

    float hv0 = h0[b * 3 + 0], hv1 = h0[b * 3 + 1], hv2 = h0[b * 3 + 2];
    float c = c0[b * 3 + kk];

    const float* pb = pre + (size_t)b * TX * 12 + kk * 4;
    float4 p = *(const float4*)(pb);

    for (int t = 0; t < TX; ++t) {
        const float4 pn = *(const float4*)(pb + (size_t)((t + 1 < TX) ? t + 1 : t) * 12);

        float a0 = p.x, a1 = p.y, a2 = p.z, a3 = p.w;   // i,f,g,o
        a0 = fmaf(wh[0][0], hv0, a0); a0 = fmaf(wh[0][1], hv1, a0); a0 = fmaf(wh[0][2], hv2, a0);
        a1 = fmaf(wh[1][0], hv0, a1); a1 = fmaf(wh[1][1], hv1, a1); a1 = fmaf(wh[1][2], hv2, a1);
        a2 = fmaf(wh[2][0], hv0, a2); a2 = fmaf(wh[2][1], hv1, a2); a2 = fmaf(wh[2][2], hv2, a2);
        a3 = fmaf(wh[3][0], hv0, a3); a3 = fmaf(wh[3][1], hv1, a3); a3 = fmaf(wh[3][2], hv2, a3);

        const float ig = sigf(a0);
        const float fg = sigf(a1);
        const float gg = tanhfast(a2);
        const float og = sigf(a3);
        c = fmaf(fg, c, ig * gg);
        const float hk = og * tanhfast(c);
        hv0 = dpp_f32<DPP_BC0>(hk);
        hv1 = dpp_f32<DPP_BC1>(hk);
        hv2 = dpp_f32<DPP_BC2>(hk);
        p = pn;
    }

    if (k == 0) {
        float zz = bfc_e[0];
        zz = fmaf(hv0, Wfc_e[0], zz);
        zz = fmaf(hv1, Wfc_e[1], zz);
        zz = fmaf(hv2, Wfc_e[2], zz);
        out_z[b] = zz;
    }
}

// ---- decoder: LSTM H=128, 4-way K-split, f16 dot2, DPP quad reduction --------
// thread (j = tid>>2, q = tid&3): all 4 gate rows for col j over k in [32q,32q+32).
// Weights held as half2 (64 VGPR) so total static need ~118 fits the 128-VGPR
// cap the backend enforces for 512-thread WGs (R5-R7: f32 weights spilled).
// h is carried in f16 in LDS (f32 master value kept for the output).
__global__ __launch_bounds__(512) void dec_kernel(
    const float* __restrict__ s, const float* __restrict__ z,
    const float* __restrict__ Wd_ih, const float* __restrict__ Wd_hh,
    const float* __restrict__ bd_ih, const float* __restrict__ bd_hh,
    const float* __restrict__ Wfc_d, const float* __restrict__ bfc_d,
    float* __restrict__ out_traj, float* __restrict__ out_h)
{
    // h as 128 f16 = 64 dwords, double-buffered. Chunk q reads dwords
    // [16q,16q+16): quad lanes hit banks {0..3,16..19} pairwise -> 2-way (free).
    __shared__ int hbuf[2][64];

    const int b   = blockIdx.x;
    const int tid = threadIdx.x;
    const int j   = tid >> 2;    // h-col 0..127
    const int q   = tid & 3;     // K-quarter

    // ---- fused traj_hat: thread tid handles time step tid, both comps ----
    {
        const int t = tid;
        const float* st = s + ((size_t)b * TS + t) * 6;
        const float2 sa = *(const float2*)(st);
        const float2 sbb = *(const float2*)(st + 2);
        const float2 sc = *(const float2*)(st + 4);
        float o0 = bfc_d[0];
        o0 = fmaf(sa.x,  Wfc_d[0], o0); o0 = fmaf(sa.y,  Wfc_d[1], o0);
        o0 = fmaf(sbb.x, Wfc_d[2], o0); o0 = fmaf(sbb.y, Wfc_d[3], o0);
        o0 = fmaf(sc.x,  Wfc_d[4], o0); o0 = fmaf(sc.y,  Wfc_d[5], o0);
        float o1 = bfc_d[1];
        o1 = fmaf(sa.x,  Wfc_d[6],  o1); o1 = fmaf(sa.y,  Wfc_d[7],  o1);
        o1 = fmaf(sbb.x, Wfc_d[8],  o1); o1 = fmaf(sbb.y, Wfc_d[9],  o1);
        o1 = fmaf(sc.x,  Wfc_d[10], o1); o1 = fmaf(sc.y,  Wfc_d[11], o1);
        *(float2*)(out_traj + ((size_t)b * TS + t) * 2) = make_float2(o0, o1);
    }

    // Whh K-slices for the 4 gates of col j, converted to half2 (16 per gate)
    h2 w[4][16];
    #pragma unroll
    for (int g = 0; g < 4; ++g) {
        const float* wp = Wd_hh + (size_t)(g * DH + j) * DH + q * 32;
        #pragma unroll
        for (int k = 0; k < 16; ++k)
            w[g][k] = h2{(_Float16)wp[2 * k], (_Float16)wp[2 * k + 1]};
    }
    // x-part: lane q owns gate q's s-dot (f32)
    const float* wi = Wd_ih + (size_t)(q * DH + j) * 7;
    const float wx0 = wi[0], wx1 = wi[1], wx2 = wi[2];
    const float wx3 = wi[3], wx4 = wi[4], wx5 = wi[5];
    const float gb  = bd_ih[q * DH + j] + bd_hh[q * DH + j] + z[b] * wi[6];

    if (tid < 64) hbuf[0][tid] = 0;
    float c = 0.0f;
    float hn = 0.0f;
    __syncthreads();

    const float* sb = s + (size_t)b * TS * 6;
    float2 sA = *(const float2*)(sb);
    float2 sB = *(const float2*)(sb + 2);
    float2 sC = *(const float2*)(sb + 4);

    for (int t = 0; t < TS; ++t) {
        const float* sn = sb + (size_t)((t + 1 < TS) ? t + 1 : t) * 6;
        const float2 nA = *(const float2*)(sn);
        const float2 nB = *(const float2*)(sn + 2);
        const float2 nC = *(const float2*)(sn + 4);

        // h chunk: 4 x ds_read_b128 (16 half2)
        const int4* hb = (const int4*)(&hbuf[t & 1][q * 16]);
        const int4 hA = hb[0], hB = hb[1], hC = hb[2], hD = hb[3];
        h2 hh[16];
        hh[0]  = __builtin_bit_cast(h2, hA.x); hh[1]  = __builtin_bit_cast(h2, hA.y);
        hh[2]  = __builtin_bit_cast(h2, hA.z); hh[3]  = __builtin_bit_cast(h2, hA.w);
        hh[4]  = __builtin_bit_cast(h2, hB.x); hh[5]  = __builtin_bit_cast(h2, hB.y);
        hh[6]  = __builtin_bit_cast(h2, hB.z); hh[7]  = __builtin_bit_cast(h2, hB.w);
        hh[8]  = __builtin_bit_cast(h2, hC.x); hh[9]  = __builtin_bit_cast(h2, hC.y);
        hh[10] = __builtin_bit_cast(h2, hC.z); hh[11] = __builtin_bit_cast(h2, hC.w);
        hh[12] = __builtin_bit_cast(h2, hD.x); hh[13] = __builtin_bit_cast(h2, hD.y);
        hh[14] = __builtin_bit_cast(h2, hD.z); hh[15] = __builtin_bit_cast(h2, hD.w);

        // s-dot for gate q (f32)
        float sdot = gb;
        sdot = fmaf(wx0, sA.x, sdot);
        sdot = fmaf(wx1, sA.y, sdot);
        sdot = fmaf(wx2, sB.x, sdot);
        sdot = fmaf(wx3, sB.y, sdot);
        sdot = fmaf(wx4, sC.x, sdot);
        sdot = fmaf(wx5, sC.y, sdot);

        // partial dots: 16 dot2 per gate, f32 accumulate
        float acc[4];
        #pragma unroll
        for (int g = 0; g < 4; ++g) {
            float p = (g == q) ? sdot : 0.0f;
            #pragma unroll
            for (int k = 0; k < 16; ++k)
                p = __builtin_amdgcn_fdot2(w[g][k], hh[k], p, false);
            acc[g] = p;
        }

        // quad butterfly (VALU DPP)
        #pragma unroll
        for (int g = 0; g < 4; ++g) {
            float v = acc[g];
            v += dpp_f32<DPP_XOR1>(v);
            v += dpp_f32<DPP_XOR2>(v);
            acc[g] = v;
        }

        const float ig = sigf(acc[0]);
        const float fg = sigf(acc[1]);
        const float gg = tanhfast(acc[2]);
        const float og = sigf(acc[3]);
        c  = fmaf(fg, c, ig * gg);
        hn = og * tanhfast(c);

        if (q == 0) ((_Float16*)hbuf[(t + 1) & 1])[j] = (_Float16)hn;
        __syncthreads();

        sA = nA; sB = nB; sC = nC;
    }

    if (q == 0) out_h[(size_t)b * DH + j] = hn;
}

extern "C" void kernel_launch(void* const* d_in, const int* in_sizes, int n_in,
                              void* d_out, int out_size, void* d_ws, size_t ws_size,
                              hipStream_t stream) {
    const float* x      = (const float*)d_in[0];
    const float* s      = (const float*)d_in[1];
    const float* h0     = (const float*)d_in[2];
    const float* c0     = (const float*)d_in[3];
    const float* We_ih  = (const float*)d_in[4];
    const float* We_hh  = (const float*)d_in[5];
    const float* be_ih  = (const float*)d_in[6];
    const float* be_hh  = (const float*)d_in[7];
    const float* Wfc_e  = (const float*)d_in[8];
    const float* bfc_e  = (const float*)d_in[9];
    const float* Wd_ih  = (const float*)d_in[10];
    const float* Wd_hh  = (const float*)d_in[11];
    const float* bd_ih  = (const float*)d_in[12];
    const float* bd_hh  = (const float*)d_in[13];
    const float* Wfc_d  = (const float*)d_in[14];
    const float* bfc_d  = (const float*)d_in[15];

    float* out      = (float*)d_out;
    float* out_z    = out;                           // [256]
    float* out_traj = out + BATCH;                   // [256*512*2]
    float* out_h    = out + BATCH + BATCH * TS * 2;  // [256*128]

    float* pre = (float*)d_ws;                       // [256][512][12] = 6.3 MB

    enc_pre_kernel<<<BATCH, 512, 0, stream>>>(x, We_ih, be_ih, be_hh, pre);
    enc_kernel<<<16, 64, 0, stream>>>(pre, h0, c0, We_hh, Wfc_e, bfc_e, out_z);
    dec_kernel<<<BATCH, 512, 0, stream>>>(s, out_z, Wd_ih, Wd_hh, bd_ih, bd_hh,
                                          Wfc_d, bfc_d, out_traj, out_h);
}

// Round 10
// 482.519 us; speedup vs baseline: 1.4532x; 1.0525x over previous
//
#include <hip/hip_runtime.h>
#include <math.h>

#define BATCH 256
#define TX 512
#define TS 512
#define DH 128

typedef _Float16 h2 __attribute__((ext_vector_type(2)));

__device__ __forceinline__ float sigf(float x) {
    return __builtin_amdgcn_rcpf(1.0f + __expf(-x));
}
__device__ __forceinline__ float tanhfast(float x) {
    return fmaf(-2.0f, __builtin_amdgcn_rcpf(__expf(2.0f * x) + 1.0f), 1.0f);
}
template<int CTRL>
__device__ __forceinline__ float dpp_f32(float x) {
    return __int_as_float(__builtin_amdgcn_update_dpp(
        0, __float_as_int(x), CTRL, 0xF, 0xF, true));
}
#define DPP_XOR1 0xB1  // quad_perm [1,0,3,2]
#define DPP_XOR2 0x4E  // quad_perm [2,3,0,1]
#define DPP_BC0  0x00
#define DPP_BC1  0x55
#define DPP_BC2  0xAA

// ---- enc_pre: x-part of encoder gates, fully parallel ------------------------
__global__ __launch_bounds__(512) void enc_pre_kernel(
    const float* __restrict__ x,
    const float* __restrict__ We_ih, const float* __restrict__ be_ih,
    const float* __restrict__ be_hh, float* __restrict__ pre)
{
    const int b = blockIdx.x, t = threadIdx.x;
    const float* xp = x + ((size_t)b * TX + t) * 8;
    const float4 x0 = *(const float4*)(xp);
    const float4 x1 = *(const float4*)(xp + 4);

    float o[12];
    #pragma unroll
    for (int g = 0; g < 4; ++g) {
        #pragma unroll
        for (int kk = 0; kk < 3; ++kk) {
            const int row = g * 3 + kk;
            const float* wr = We_ih + row * 8;
            float d = be_ih[row] + be_hh[row];
            d = fmaf(wr[0], x0.x, d); d = fmaf(wr[1], x0.y, d);
            d = fmaf(wr[2], x0.z, d); d = fmaf(wr[3], x0.w, d);
            d = fmaf(wr[4], x1.x, d); d = fmaf(wr[5], x1.y, d);
            d = fmaf(wr[6], x1.z, d); d = fmaf(wr[7], x1.w, d);
            o[kk * 4 + g] = d;
        }
    }
    float* op = pre + ((size_t)b * TX + t) * 12;
    *(float4*)(op)     = make_float4(o[0], o[1], o[2],  o[3]);
    *(float4*)(op + 4) = make_float4(o[4], o[5], o[6],  o[7]);
    *(float4*)(op + 8) = make_float4(o[8], o[9], o[10], o[11]);
}

// ---- encoder serial: only the h-recurrence; 3-deep prefetch ------------------
__global__ __launch_bounds__(64) void enc_kernel(
    const float* __restrict__ pre, const float* __restrict__ h0,
    const float* __restrict__ c0, const float* __restrict__ We_hh,
    const float* __restrict__ Wfc_e, const float* __restrict__ bfc_e,
    float* __restrict__ out_z)
{
    const int gt = blockIdx.x * 64 + threadIdx.x;
    const int b  = gt >> 2;
    const int k  = gt & 3;
    const int kk = (k < 3) ? k : 0;

    float wh[4][3];
    #pragma unroll
    for (int g = 0; g < 4; ++g) {
        const int row = g * 3 + kk;
        #pragma unroll
        for (int n = 0; n < 3; ++n) wh[g][n] = We_hh[row * 3 + n];
    }

    float hv0 = h0[b * 3 + 0], hv1 = h0[b * 3 + 1], hv2 = h0[b * 3 + 2];
    float c = c0[b * 3 + kk];

    const float* pb = pre + (size_t)b * TX * 12 + kk * 4;
    // 3-deep prefetch pipeline: L2 latency ~200cyc > ~90cyc step, 1-deep stalled
    float4 P0 = *(const float4*)(pb);
    float4 P1 = *(const float4*)(pb + 12);
    float4 P2 = *(const float4*)(pb + 24);

    for (int t = 0; t < TX; ++t) {
        const int tn = (t + 3 < TX) ? t + 3 : TX - 1;
        const float4 pn = *(const float4*)(pb + (size_t)tn * 12);

        float a0 = P0.x, a1 = P0.y, a2 = P0.z, a3 = P0.w;   // i,f,g,o
        a0 = fmaf(wh[0][0], hv0, a0); a0 = fmaf(wh[0][1], hv1, a0); a0 = fmaf(wh[0][2], hv2, a0);
        a1 = fmaf(wh[1][0], hv0, a1); a1 = fmaf(wh[1][1], hv1, a1); a1 = fmaf(wh[1][2], hv2, a1);
        a2 = fmaf(wh[2][0], hv0, a2); a2 = fmaf(wh[2][1], hv1, a2); a2 = fmaf(wh[2][2], hv2, a2);
        a3 = fmaf(wh[3][0], hv0, a3); a3 = fmaf(wh[3][1], hv1, a3); a3 = fmaf(wh[3][2], hv2, a3);

        const float ig = sigf(a0);
        const float fg = sigf(a1);
        const float gg = tanhfast(a2);
        const float og = sigf(a3);
        c = fmaf(fg, c, ig * gg);
        const float hk = og * tanhfast(c);
        hv0 = dpp_f32<DPP_BC0>(hk);
        hv1 = dpp_f32<DPP_BC1>(hk);
        hv2 = dpp_f32<DPP_BC2>(hk);
        P0 = P1; P1 = P2; P2 = pn;
    }

    if (k == 0) {
        float zz = bfc_e[0];
        zz = fmaf(hv0, Wfc_e[0], zz);
        zz = fmaf(hv1, Wfc_e[1], zz);
        zz = fmaf(hv2, Wfc_e[2], zz);
        out_z[b] = zz;
    }
}

// ---- decoder: LSTM H=128, 4-way K-split, f16 dot2, DPP quad reduction --------
// (512,1): raises the VGPR cap to 128 (R5 evidence) -- static need ~90, so the
// allocator gets headroom to keep live ranges in place instead of v_mov folding
// (R9: VGPR_Count=80 exactly at the no-hint budget, suspected copy bloat).
__global__ __launch_bounds__(512, 1) void dec_kernel(
    const float* __restrict__ s, const float* __restrict__ z,
    const float* __restrict__ Wd_ih, const float* __restrict__ Wd_hh,
    const float* __restrict__ bd_ih, const float* __restrict__ bd_hh,
    const float* __restrict__ Wfc_d, const float* __restrict__ bfc_d,
    float* __restrict__ out_traj, float* __restrict__ out_h)
{
    __shared__ int hbuf[2][64];

    const int b   = blockIdx.x;
    const int tid = threadIdx.x;
    const int j   = tid >> 2;    // h-col 0..127
    const int q   = tid & 3;     // K-quarter

    // ---- fused traj_hat ----
    {
        const int t = tid;
        const float* st = s + ((size_t)b * TS + t) * 6;
        const float2 sa = *(const float2*)(st);
        const float2 sbb = *(const float2*)(st + 2);
        const float2 sc = *(const float2*)(st + 4);
        float o0 = bfc_d[0];
        o0 = fmaf(sa.x,  Wfc_d[0], o0); o0 = fmaf(sa.y,  Wfc_d[1], o0);
        o0 = fmaf(sbb.x, Wfc_d[2], o0); o0 = fmaf(sbb.y, Wfc_d[3], o0);
        o0 = fmaf(sc.x,  Wfc_d[4], o0); o0 = fmaf(sc.y,  Wfc_d[5], o0);
        float o1 = bfc_d[1];
        o1 = fmaf(sa.x,  Wfc_d[6],  o1); o1 = fmaf(sa.y,  Wfc_d[7],  o1);
        o1 = fmaf(sbb.x, Wfc_d[8],  o1); o1 = fmaf(sbb.y, Wfc_d[9],  o1);
        o1 = fmaf(sc.x,  Wfc_d[10], o1); o1 = fmaf(sc.y,  Wfc_d[11], o1);
        *(float2*)(out_traj + ((size_t)b * TS + t) * 2) = make_float2(o0, o1);
    }

    // Whh K-slices for the 4 gates of col j, f16 (64 VGPR)
    h2 w[4][16];
    #pragma unroll
    for (int g = 0; g < 4; ++g) {
        const float* wp = Wd_hh + (size_t)(g * DH + j) * DH + q * 32;
        #pragma unroll
        for (int k = 0; k < 16; ++k)
            w[g][k] = h2{(_Float16)wp[2 * k], (_Float16)wp[2 * k + 1]};
    }
    // x-part: lane q owns gate q's s-dot (f32)
    const float* wi = Wd_ih + (size_t)(q * DH + j) * 7;
    const float wx0 = wi[0], wx1 = wi[1], wx2 = wi[2];
    const float wx3 = wi[3], wx4 = wi[4], wx5 = wi[5];
    const float gb  = bd_ih[q * DH + j] + bd_hh[q * DH + j] + z[b] * wi[6];

    if (tid < 64) hbuf[0][tid] = 0;
    float c = 0.0f;
    float hn = 0.0f;
    __syncthreads();

    const float* sb = s + (size_t)b * TS * 6;
    float2 sA = *(const float2*)(sb);
    float2 sB = *(const float2*)(sb + 2);
    float2 sC = *(const float2*)(sb + 4);
    const float* sp = sb + 6;

#define DEC_STEP(T)                                                            \
    {                                                                          \
        const int4* hb = (const int4*)(&hbuf[(T) & 1][q * 16]);                \
        const int4 hA = hb[0], hB = hb[1], hC = hb[2], hD = hb[3];             \
        h2 hh[16];                                                             \
        hh[0]  = __builtin_bit_cast(h2, hA.x); hh[1]  = __builtin_bit_cast(h2, hA.y); \
        hh[2]  = __builtin_bit_cast(h2, hA.z); hh[3]  = __builtin_bit_cast(h2, hA.w); \
        hh[4]  = __builtin_bit_cast(h2, hB.x); hh[5]  = __builtin_bit_cast(h2, hB.y); \
        hh[6]  = __builtin_bit_cast(h2, hB.z); hh[7]  = __builtin_bit_cast(h2, hB.w); \
        hh[8]  = __builtin_bit_cast(h2, hC.x); hh[9]  = __builtin_bit_cast(h2, hC.y); \
        hh[10] = __builtin_bit_cast(h2, hC.z); hh[11] = __builtin_bit_cast(h2, hC.w); \
        hh[12] = __builtin_bit_cast(h2, hD.x); hh[13] = __builtin_bit_cast(h2, hD.y); \
        hh[14] = __builtin_bit_cast(h2, hD.z); hh[15] = __builtin_bit_cast(h2, hD.w); \
        float sdot = gb;                                                       \
        sdot = fmaf(wx0, sA.x, sdot);                                          \
        sdot = fmaf(wx1, sA.y, sdot);                                          \
        sdot = fmaf(wx2, sB.x, sdot);                                          \
        sdot = fmaf(wx3, sB.y, sdot);                                          \
        sdot = fmaf(wx4, sC.x, sdot);                                          \
        sdot = fmaf(wx5, sC.y, sdot);                                          \
        float acc[4];                                                          \
        _Pragma("unroll")                                                      \
        for (int g = 0; g < 4; ++g) {                                          \
            float p = (g == q) ? sdot : 0.0f;                                  \
            _Pragma("unroll")                                                  \
            for (int k = 0; k < 16; ++k)                                       \
                p = __builtin_amdgcn_fdot2(w[g][k], hh[k], p, false);          \
            acc[g] = p;                                                        \
        }                                                                      \
        _Pragma("unroll")                                                      \
        for (int g = 0; g < 4; ++g) {                                          \
            float v = acc[g];                                                  \
            v += dpp_f32<DPP_XOR1>(v);                                         \
            v += dpp_f32<DPP_XOR2>(v);                                         \
            acc[g] = v;                                                        \
        }                                                                      \
        const float ig = sigf(acc[0]);                                         \
        const float fg = sigf(acc[1]);                                         \
        const float gg = tanhfast(acc[2]);                                     \
        const float og = sigf(acc[3]);                                         \
        c  = fmaf(fg, c, ig * gg);                                             \
        hn = og * tanhfast(c);                                                 \
        if (q == 0) ((_Float16*)hbuf[((T) + 1) & 1])[j] = (_Float16)hn;        \
        __syncthreads();                                                       \
    }

    for (int t = 0; t < TS - 1; ++t) {
        const float2 nA = *(const float2*)(sp);
        const float2 nB = *(const float2*)(sp + 2);
        const float2 nC = *(const float2*)(sp + 4);
        sp += 6;
        DEC_STEP(t);
        sA = nA; sB = nB; sC = nC;
    }
    DEC_STEP(TS - 1);
#undef DEC_STEP

    if (q == 0) out_h[(size_t)b * DH + j] = hn;
}

extern "C" void kernel_launch(void* const* d_in, const int* in_sizes, int n_in,
                              void* d_out, int out_size, void* d_ws, size_t ws_size,
                              hipStream_t stream) {
    const float* x      = (const float*)d_in[0];
    const float* s      = (const float*)d_in[1];
    const float* h0     = (const float*)d_in[2];
    const float* c0     = (const float*)d_in[3];
    const float* We_ih  = (const float*)d_in[4];
    const float* We_hh  = (const float*)d_in[5];
    const float* be_ih  = (const float*)d_in[6];
    const float* be_hh  = (const float*)d_in[7];
    const float* Wfc_e  = (const float*)d_in[8];
    const float* bfc_e  = (const float*)d_in[9];
    const float* Wd_ih  = (const float*)d_in[10];
    const float* Wd_hh  = (const float*)d_in[11];
    const float* bd_ih  = (const float*)d_in[12];
    const float* bd_hh  = (const float*)d_in[13];
    const float* Wfc_d  = (const float*)d_in[14];
    const float* bfc_d  = (const float*)d_in[15];

    float* out      = (float*)d_out;
    float* out_z    = out;                           // [256]
    float* out_traj = out + BATCH;                   // [256*512*2]
    float* out_h    = out + BATCH + BATCH * TS * 2;  // [256*128]

    float* pre = (float*)d_ws;                       // [256][512][12] = 6.3 MB

    enc_pre_kernel<<<BATCH, 512, 0, stream>>>(x, We_ih, be_ih, be_hh, pre);
    enc_kernel<<<16, 64, 0, stream>>>(pre, h0, c0, We_hh, Wfc_e, bfc_e, out_z);
    dec_kernel<<<BATCH, 512, 0, stream>>>(s, out_z, Wd_ih, Wd_hh, bd_ih, bd_hh,
                                          Wfc_d, bfc_d, out_traj, out_h);
}

// Round 11
// 452.611 us; speedup vs baseline: 1.5492x; 1.0661x over previous
//
#include <hip/hip_runtime.h>
#include <math.h>

#define BATCH 256
#define TX 512
#define TS 512
#define DH 128

typedef _Float16 h2 __attribute__((ext_vector_type(2)));

__device__ __forceinline__ float sigf(float x) {
    return __builtin_amdgcn_rcpf(1.0f + __expf(-x));
}
__device__ __forceinline__ float tanhfast(float x) {
    return fmaf(-2.0f, __builtin_amdgcn_rcpf(__expf(2.0f * x) + 1.0f), 1.0f);
}
template<int CTRL>
__device__ __forceinline__ float dpp_f32(float x) {
    return __int_as_float(__builtin_amdgcn_update_dpp(
        0, __float_as_int(x), CTRL, 0xF, 0xF, true));
}
#define DPP_XOR1 0xB1  // quad_perm [1,0,3,2]
#define DPP_XOR2 0x4E  // quad_perm [2,3,0,1]
#define DPP_BC0  0x00
#define DPP_BC1  0x55
#define DPP_BC2  0xAA

// ================= fully fused: enc_pre + encoder + traj + decoder ===========
// One WG (512 thr) per batch element b.
//  A: all threads: x-part of encoder gates -> pre_lds (24KB), traj_hat store,
//     decoder weight loads (overlap).
//  B: lanes 0-3: serial encoder (512 steps) from pre_lds -> z (LDS broadcast).
//  C: all threads: decoder (4-way K-split, f16 dot2, DPP quad butterfly),
//     2-step ping-pong unroll (no s-copy movs, compile-time hbuf index).
__global__ __launch_bounds__(512) void fused_kernel(
    const float* __restrict__ x, const float* __restrict__ s,
    const float* __restrict__ h0, const float* __restrict__ c0,
    const float* __restrict__ We_ih, const float* __restrict__ We_hh,
    const float* __restrict__ be_ih, const float* __restrict__ be_hh,
    const float* __restrict__ Wfc_e, const float* __restrict__ bfc_e,
    const float* __restrict__ Wd_ih, const float* __restrict__ Wd_hh,
    const float* __restrict__ bd_ih, const float* __restrict__ bd_hh,
    const float* __restrict__ Wfc_d, const float* __restrict__ bfc_d,
    float* __restrict__ out_z, float* __restrict__ out_traj,
    float* __restrict__ out_h)
{
    __shared__ __align__(16) float pre_lds[TX][12];   // 24 KB
    __shared__ int hbuf[2][64];
    __shared__ float zslot;

    const int b   = blockIdx.x;
    const int tid = threadIdx.x;
    const int j   = tid >> 2;    // h-col 0..127
    const int q   = tid & 3;     // K-quarter

    // ---- phase A: encoder x-gates into LDS (thread t = tid) ----
    {
        const float* xp = x + ((size_t)b * TX + tid) * 8;
        const float4 x0 = *(const float4*)(xp);
        const float4 x1 = *(const float4*)(xp + 4);
        float o[12];
        #pragma unroll
        for (int g = 0; g < 4; ++g) {
            #pragma unroll
            for (int kk = 0; kk < 3; ++kk) {
                const int row = g * 3 + kk;
                const float* wr = We_ih + row * 8;
                float d = be_ih[row] + be_hh[row];
                d = fmaf(wr[0], x0.x, d); d = fmaf(wr[1], x0.y, d);
                d = fmaf(wr[2], x0.z, d); d = fmaf(wr[3], x0.w, d);
                d = fmaf(wr[4], x1.x, d); d = fmaf(wr[5], x1.y, d);
                d = fmaf(wr[6], x1.z, d); d = fmaf(wr[7], x1.w, d);
                o[kk * 4 + g] = d;
            }
        }
        float* op = pre_lds[tid];
        *(float4*)(op)     = make_float4(o[0], o[1], o[2],  o[3]);
        *(float4*)(op + 4) = make_float4(o[4], o[5], o[6],  o[7]);
        *(float4*)(op + 8) = make_float4(o[8], o[9], o[10], o[11]);
    }
    if (tid < 64) hbuf[0][tid] = 0;

    // ---- fused traj_hat (independent of z; overlaps phase B) ----
    {
        const float* st = s + ((size_t)b * TS + tid) * 6;
        const float2 sa = *(const float2*)(st);
        const float2 sbb = *(const float2*)(st + 2);
        const float2 sc = *(const float2*)(st + 4);
        float o0 = bfc_d[0];
        o0 = fmaf(sa.x,  Wfc_d[0], o0); o0 = fmaf(sa.y,  Wfc_d[1], o0);
        o0 = fmaf(sbb.x, Wfc_d[2], o0); o0 = fmaf(sbb.y, Wfc_d[3], o0);
        o0 = fmaf(sc.x,  Wfc_d[4], o0); o0 = fmaf(sc.y,  Wfc_d[5], o0);
        float o1 = bfc_d[1];
        o1 = fmaf(sa.x,  Wfc_d[6],  o1); o1 = fmaf(sa.y,  Wfc_d[7],  o1);
        o1 = fmaf(sbb.x, Wfc_d[8],  o1); o1 = fmaf(sbb.y, Wfc_d[9],  o1);
        o1 = fmaf(sc.x,  Wfc_d[10], o1); o1 = fmaf(sc.y,  Wfc_d[11], o1);
        *(float2*)(out_traj + ((size_t)b * TS + tid) * 2) = make_float2(o0, o1);
    }

    // ---- decoder weight loads (independent of z; overlaps phase B) ----
    h2 w[4][16];
    #pragma unroll
    for (int g = 0; g < 4; ++g) {
        const float* wp = Wd_hh + (size_t)(g * DH + j) * DH + q * 32;
        #pragma unroll
        for (int k = 0; k < 16; ++k)
            w[g][k] = h2{(_Float16)wp[2 * k], (_Float16)wp[2 * k + 1]};
    }
    const float* wi = Wd_ih + (size_t)(q * DH + j) * 7;
    const float wx0 = wi[0], wx1 = wi[1], wx2 = wi[2];
    const float wx3 = wi[3], wx4 = wi[4], wx5 = wi[5];
    const float bsum = bd_ih[q * DH + j] + bd_hh[q * DH + j];
    const float wz = wi[6];

    __syncthreads();   // pre_lds ready

    // ---- phase B: serial encoder on lanes 0..3 ----
    if (tid < 4) {
        const int kk = (tid < 3) ? tid : 0;
        float wh[4][3];
        #pragma unroll
        for (int g = 0; g < 4; ++g) {
            const int row = g * 3 + kk;
            #pragma unroll
            for (int n = 0; n < 3; ++n) wh[g][n] = We_hh[row * 3 + n];
        }
        float hv0 = h0[b * 3 + 0], hv1 = h0[b * 3 + 1], hv2 = h0[b * 3 + 2];
        float c = c0[b * 3 + kk];

        float4 P = *(const float4*)(&pre_lds[0][kk * 4]);
        for (int t = 0; t < TX; ++t) {
            const int tn = (t + 1 < TX) ? t + 1 : t;
            const float4 Pn = *(const float4*)(&pre_lds[tn][kk * 4]);

            float a0 = P.x, a1 = P.y, a2 = P.z, a3 = P.w;   // i,f,g,o
            a0 = fmaf(wh[0][0], hv0, a0); a0 = fmaf(wh[0][1], hv1, a0); a0 = fmaf(wh[0][2], hv2, a0);
            a1 = fmaf(wh[1][0], hv0, a1); a1 = fmaf(wh[1][1], hv1, a1); a1 = fmaf(wh[1][2], hv2, a1);
            a2 = fmaf(wh[2][0], hv0, a2); a2 = fmaf(wh[2][1], hv1, a2); a2 = fmaf(wh[2][2], hv2, a2);
            a3 = fmaf(wh[3][0], hv0, a3); a3 = fmaf(wh[3][1], hv1, a3); a3 = fmaf(wh[3][2], hv2, a3);

            const float ig = sigf(a0);
            const float fg = sigf(a1);
            const float gg = tanhfast(a2);
            const float og = sigf(a3);
            c = fmaf(fg, c, ig * gg);
            const float hk = og * tanhfast(c);
            hv0 = dpp_f32<DPP_BC0>(hk);
            hv1 = dpp_f32<DPP_BC1>(hk);
            hv2 = dpp_f32<DPP_BC2>(hk);
            P = Pn;
        }
        if (tid == 0) {
            float zz = bfc_e[0];
            zz = fmaf(hv0, Wfc_e[0], zz);
            zz = fmaf(hv1, Wfc_e[1], zz);
            zz = fmaf(hv2, Wfc_e[2], zz);
            zslot = zz;
            out_z[b] = zz;
        }
    }
    __syncthreads();   // z ready

    const float gb = bsum + zslot * wz;

    // ---- phase C: decoder ----
    float c = 0.0f;
    float hn = 0.0f;

    const float* sb = s + (size_t)b * TS * 6;
    float2 sA = *(const float2*)(sb);
    float2 sB = *(const float2*)(sb + 2);
    float2 sC = *(const float2*)(sb + 4);
    float2 sD = *(const float2*)(sb + 6);
    float2 sE = *(const float2*)(sb + 8);
    float2 sF = *(const float2*)(sb + 10);

#define DEC_STEP(BUF, XA, XB, XC)                                              \
    {                                                                          \
        const int4* hb = (const int4*)(&hbuf[BUF][q * 16]);                    \
        const int4 hA = hb[0], hB = hb[1], hC = hb[2], hD = hb[3];             \
        float sdot = gb;                                                       \
        sdot = fmaf(wx0, XA.x, sdot);                                          \
        sdot = fmaf(wx1, XA.y, sdot);                                          \
        sdot = fmaf(wx2, XB.x, sdot);                                          \
        sdot = fmaf(wx3, XB.y, sdot);                                          \
        sdot = fmaf(wx4, XC.x, sdot);                                          \
        sdot = fmaf(wx5, XC.y, sdot);                                          \
        h2 hh[16];                                                             \
        hh[0]  = __builtin_bit_cast(h2, hA.x); hh[1]  = __builtin_bit_cast(h2, hA.y); \
        hh[2]  = __builtin_bit_cast(h2, hA.z); hh[3]  = __builtin_bit_cast(h2, hA.w); \
        hh[4]  = __builtin_bit_cast(h2, hB.x); hh[5]  = __builtin_bit_cast(h2, hB.y); \
        hh[6]  = __builtin_bit_cast(h2, hB.z); hh[7]  = __builtin_bit_cast(h2, hB.w); \
        hh[8]  = __builtin_bit_cast(h2, hC.x); hh[9]  = __builtin_bit_cast(h2, hC.y); \
        hh[10] = __builtin_bit_cast(h2, hC.z); hh[11] = __builtin_bit_cast(h2, hC.w); \
        hh[12] = __builtin_bit_cast(h2, hD.x); hh[13] = __builtin_bit_cast(h2, hD.y); \
        hh[14] = __builtin_bit_cast(h2, hD.z); hh[15] = __builtin_bit_cast(h2, hD.w); \
        float acc[4];                                                          \
        _Pragma("unroll")                                                      \
        for (int g = 0; g < 4; ++g) {                                          \
            float p = (g == q) ? sdot : 0.0f;                                  \
            _Pragma("unroll")                                                  \
            for (int k = 0; k < 16; ++k)                                       \
                p = __builtin_amdgcn_fdot2(w[g][k], hh[k], p, false);          \
            acc[g] = p;                                                        \
        }                                                                      \
        _Pragma("unroll")                                                      \
        for (int g = 0; g < 4; ++g) {                                          \
            float v = acc[g];                                                  \
            v += dpp_f32<DPP_XOR1>(v);                                         \
            v += dpp_f32<DPP_XOR2>(v);                                         \
            acc[g] = v;                                                        \
        }                                                                      \
        const float ig = sigf(acc[0]);                                         \
        const float fg = sigf(acc[1]);                                         \
        const float gg = tanhfast(acc[2]);                                     \
        const float og = sigf(acc[3]);                                         \
        c  = fmaf(fg, c, ig * gg);                                             \
        hn = og * tanhfast(c);                                                 \
        if (q == 0) ((_Float16*)hbuf[BUF ^ 1])[j] = (_Float16)hn;              \
        __syncthreads();                                                       \
    }

    for (int t = 0; t < TS; t += 2) {
        DEC_STEP(0, sA, sB, sC);
        {
            const int tn = (t + 2 < TS) ? t + 2 : TS - 1;
            const float* p = sb + (size_t)tn * 6;
            sA = *(const float2*)(p);
            sB = *(const float2*)(p + 2);
            sC = *(const float2*)(p + 4);
        }
        DEC_STEP(1, sD, sE, sF);
        {
            const int tn = (t + 3 < TS) ? t + 3 : TS - 1;
            const float* p = sb + (size_t)tn * 6;
            sD = *(const float2*)(p);
            sE = *(const float2*)(p + 2);
            sF = *(const float2*)(p + 4);
        }
    }
#undef DEC_STEP

    if (q == 0) out_h[(size_t)b * DH + j] = hn;
}

extern "C" void kernel_launch(void* const* d_in, const int* in_sizes, int n_in,
                              void* d_out, int out_size, void* d_ws, size_t ws_size,
                              hipStream_t stream) {
    const float* x      = (const float*)d_in[0];
    const float* s      = (const float*)d_in[1];
    const float* h0     = (const float*)d_in[2];
    const float* c0     = (const float*)d_in[3];
    const float* We_ih  = (const float*)d_in[4];
    const float* We_hh  = (const float*)d_in[5];
    const float* be_ih  = (const float*)d_in[6];
    const float* be_hh  = (const float*)d_in[7];
    const float* Wfc_e  = (const float*)d_in[8];
    const float* bfc_e  = (const float*)d_in[9];
    const float* Wd_ih  = (const float*)d_in[10];
    const float* Wd_hh  = (const float*)d_in[11];
    const float* bd_ih  = (const float*)d_in[12];
    const float* bd_hh  = (const float*)d_in[13];
    const float* Wfc_d  = (const float*)d_in[14];
    const float* bfc_d  = (const float*)d_in[15];

    float* out      = (float*)d_out;
    float* out_z    = out;                           // [256]
    float* out_traj = out + BATCH;                   // [256*512*2]
    float* out_h    = out + BATCH + BATCH * TS * 2;  // [256*128]

    fused_kernel<<<BATCH, 512, 0, stream>>>(
        x, s, h0, c0, We_ih, We_hh, be_ih, be_hh, Wfc_e, bfc_e,
        Wd_ih, Wd_hh, bd_ih, bd_hh, Wfc_d, bfc_d,
        out_z, out_traj, out_h);
}

// Round 12
// 449.545 us; speedup vs baseline: 1.5598x; 1.0068x over previous
//
#include <hip/hip_runtime.h>
#include <math.h>

#define BATCH 256
#define TX 512
#define TS 512
#define DH 128

typedef _Float16 h2 __attribute__((ext_vector_type(2)));

__device__ __forceinline__ float sigf(float x) {
    return __builtin_amdgcn_rcpf(1.0f + __expf(-x));
}
__device__ __forceinline__ float tanhfast(float x) {
    return fmaf(-2.0f, __builtin_amdgcn_rcpf(__expf(2.0f * x) + 1.0f), 1.0f);
}
template<int CTRL>
__device__ __forceinline__ float dpp_f32(float x) {
    return __int_as_float(__builtin_amdgcn_update_dpp(
        0, __float_as_int(x), CTRL, 0xF, 0xF, true));
}
#define DPP_XOR1 0xB1  // quad_perm [1,0,3,2] : swaps lane-bit0
#define DPP_BC0  0x00
#define DPP_BC1  0x55
#define DPP_BC2  0xAA

// ================= fully fused, 256-thread WG, 2-way K-split =================
// One WG (256 thr) per batch element. Tests the cap hypothesis: VGPR budget
// scales as ~64K/WG-threads (512->128, 1024->64 observed), so 256 thr -> 256.
// Thread (j = tid>>1, q = tid&1): all 4 gate rows for h-col j over K-half
// [64q, 64q+64) as f16 dot2 (128 VGPRs of weights). Butterfly = 1 DPP/gate.
__global__ __launch_bounds__(256) void fused_kernel(
    const float* __restrict__ x, const float* __restrict__ s,
    const float* __restrict__ h0, const float* __restrict__ c0,
    const float* __restrict__ We_ih, const float* __restrict__ We_hh,
    const float* __restrict__ be_ih, const float* __restrict__ be_hh,
    const float* __restrict__ Wfc_e, const float* __restrict__ bfc_e,
    const float* __restrict__ Wd_ih, const float* __restrict__ Wd_hh,
    const float* __restrict__ bd_ih, const float* __restrict__ bd_hh,
    const float* __restrict__ Wfc_d, const float* __restrict__ bfc_d,
    float* __restrict__ out_z, float* __restrict__ out_traj,
    float* __restrict__ out_h)
{
    __shared__ __align__(16) float pre_lds[TX][12];   // 24 KB
    __shared__ int hbuf[2][64];                        // h as 128 f16
    __shared__ float zslot;

    const int b   = blockIdx.x;
    const int tid = threadIdx.x;
    const int j   = tid >> 1;    // h-col 0..127
    const int q   = tid & 1;     // K-half

    // ---- phase A: encoder x-gates into LDS (2 timesteps per thread) ----
    #pragma unroll
    for (int it = 0; it < 2; ++it) {
        const int t = tid + it * 256;
        const float* xp = x + ((size_t)b * TX + t) * 8;
        const float4 x0 = *(const float4*)(xp);
        const float4 x1 = *(const float4*)(xp + 4);
        float o[12];
        #pragma unroll
        for (int g = 0; g < 4; ++g) {
            #pragma unroll
            for (int kk = 0; kk < 3; ++kk) {
                const int row = g * 3 + kk;
                const float* wr = We_ih + row * 8;
                float d = be_ih[row] + be_hh[row];
                d = fmaf(wr[0], x0.x, d); d = fmaf(wr[1], x0.y, d);
                d = fmaf(wr[2], x0.z, d); d = fmaf(wr[3], x0.w, d);
                d = fmaf(wr[4], x1.x, d); d = fmaf(wr[5], x1.y, d);
                d = fmaf(wr[6], x1.z, d); d = fmaf(wr[7], x1.w, d);
                o[kk * 4 + g] = d;
            }
        }
        float* op = pre_lds[t];
        *(float4*)(op)     = make_float4(o[0], o[1], o[2],  o[3]);
        *(float4*)(op + 4) = make_float4(o[4], o[5], o[6],  o[7]);
        *(float4*)(op + 8) = make_float4(o[8], o[9], o[10], o[11]);
    }
    if (tid < 64) hbuf[0][tid] = 0;

    // ---- fused traj_hat (2 timesteps per thread; independent of z) ----
    #pragma unroll
    for (int it = 0; it < 2; ++it) {
        const int t = tid + it * 256;
        const float* st = s + ((size_t)b * TS + t) * 6;
        const float2 sa = *(const float2*)(st);
        const float2 sbb = *(const float2*)(st + 2);
        const float2 sc = *(const float2*)(st + 4);
        float o0 = bfc_d[0];
        o0 = fmaf(sa.x,  Wfc_d[0], o0); o0 = fmaf(sa.y,  Wfc_d[1], o0);
        o0 = fmaf(sbb.x, Wfc_d[2], o0); o0 = fmaf(sbb.y, Wfc_d[3], o0);
        o0 = fmaf(sc.x,  Wfc_d[4], o0); o0 = fmaf(sc.y,  Wfc_d[5], o0);
        float o1 = bfc_d[1];
        o1 = fmaf(sa.x,  Wfc_d[6],  o1); o1 = fmaf(sa.y,  Wfc_d[7],  o1);
        o1 = fmaf(sbb.x, Wfc_d[8],  o1); o1 = fmaf(sbb.y, Wfc_d[9],  o1);
        o1 = fmaf(sc.x,  Wfc_d[10], o1); o1 = fmaf(sc.y,  Wfc_d[11], o1);
        *(float2*)(out_traj + ((size_t)b * TS + t) * 2) = make_float2(o0, o1);
    }

    // ---- decoder weights: 4 gates x 32 h2 (K-half) = 128 VGPRs ----
    h2 w[4][32];
    #pragma unroll
    for (int g = 0; g < 4; ++g) {
        const float* wp = Wd_hh + (size_t)(g * DH + j) * DH + q * 64;
        #pragma unroll
        for (int k = 0; k < 32; ++k)
            w[g][k] = h2{(_Float16)wp[2 * k], (_Float16)wp[2 * k + 1]};
    }
    // s-dots: lane q owns gates q and q+2
    const float* wiA = Wd_ih + (size_t)(q * DH + j) * 7;
    const float* wiB = Wd_ih + (size_t)((q + 2) * DH + j) * 7;
    const float wxA0 = wiA[0], wxA1 = wiA[1], wxA2 = wiA[2];
    const float wxA3 = wiA[3], wxA4 = wiA[4], wxA5 = wiA[5];
    const float wxB0 = wiB[0], wxB1 = wiB[1], wxB2 = wiB[2];
    const float wxB3 = wiB[3], wxB4 = wiB[4], wxB5 = wiB[5];
    const float bsumA = bd_ih[q * DH + j] + bd_hh[q * DH + j];
    const float bsumB = bd_ih[(q + 2) * DH + j] + bd_hh[(q + 2) * DH + j];
    const float wzA = wiA[6], wzB = wiB[6];

    __syncthreads();   // pre_lds ready

    // ---- phase B: serial encoder on lanes 0..3 ----
    if (tid < 4) {
        const int kk = (tid < 3) ? tid : 0;
        float wh[4][3];
        #pragma unroll
        for (int g = 0; g < 4; ++g) {
            const int row = g * 3 + kk;
            #pragma unroll
            for (int n = 0; n < 3; ++n) wh[g][n] = We_hh[row * 3 + n];
        }
        float hv0 = h0[b * 3 + 0], hv1 = h0[b * 3 + 1], hv2 = h0[b * 3 + 2];
        float c = c0[b * 3 + kk];

        float4 P = *(const float4*)(&pre_lds[0][kk * 4]);
        for (int t = 0; t < TX; ++t) {
            const int tn = (t + 1 < TX) ? t + 1 : t;
            const float4 Pn = *(const float4*)(&pre_lds[tn][kk * 4]);

            float a0 = P.x, a1 = P.y, a2 = P.z, a3 = P.w;   // i,f,g,o
            a0 = fmaf(wh[0][0], hv0, a0); a0 = fmaf(wh[0][1], hv1, a0); a0 = fmaf(wh[0][2], hv2, a0);
            a1 = fmaf(wh[1][0], hv0, a1); a1 = fmaf(wh[1][1], hv1, a1); a1 = fmaf(wh[1][2], hv2, a1);
            a2 = fmaf(wh[2][0], hv0, a2); a2 = fmaf(wh[2][1], hv1, a2); a2 = fmaf(wh[2][2], hv2, a2);
            a3 = fmaf(wh[3][0], hv0, a3); a3 = fmaf(wh[3][1], hv1, a3); a3 = fmaf(wh[3][2], hv2, a3);

            const float ig = sigf(a0);
            const float fg = sigf(a1);
            const float gg = tanhfast(a2);
            const float og = sigf(a3);
            c = fmaf(fg, c, ig * gg);
            const float hk = og * tanhfast(c);
            hv0 = dpp_f32<DPP_BC0>(hk);
            hv1 = dpp_f32<DPP_BC1>(hk);
            hv2 = dpp_f32<DPP_BC2>(hk);
            P = Pn;
        }
        if (tid == 0) {
            float zz = bfc_e[0];
            zz = fmaf(hv0, Wfc_e[0], zz);
            zz = fmaf(hv1, Wfc_e[1], zz);
            zz = fmaf(hv2, Wfc_e[2], zz);
            zslot = zz;
            out_z[b] = zz;
        }
    }
    __syncthreads();   // z ready

    const float zv = zslot;
    const float gbA = bsumA + zv * wzA;
    const float gbB = bsumB + zv * wzB;

    // ---- phase C: decoder ----
    float c = 0.0f;
    float hn = 0.0f;

    const float* sb = s + (size_t)b * TS * 6;
    float2 sA = *(const float2*)(sb);
    float2 sB = *(const float2*)(sb + 2);
    float2 sC = *(const float2*)(sb + 4);
    float2 sD = *(const float2*)(sb + 6);
    float2 sE = *(const float2*)(sb + 8);
    float2 sF = *(const float2*)(sb + 10);

#define DEC_STEP(BUF, XA, XB, XC)                                              \
    {                                                                          \
        const int4* hb = (const int4*)(&hbuf[BUF][q * 32]);                    \
        const int4 H0 = hb[0], H1 = hb[1], H2 = hb[2], H3 = hb[3];             \
        const int4 H4 = hb[4], H5 = hb[5], H6 = hb[6], H7 = hb[7];             \
        float sdA = gbA;                                                       \
        sdA = fmaf(wxA0, XA.x, sdA); sdA = fmaf(wxA1, XA.y, sdA);              \
        sdA = fmaf(wxA2, XB.x, sdA); sdA = fmaf(wxA3, XB.y, sdA);              \
        sdA = fmaf(wxA4, XC.x, sdA); sdA = fmaf(wxA5, XC.y, sdA);              \
        float sdB = gbB;                                                       \
        sdB = fmaf(wxB0, XA.x, sdB); sdB = fmaf(wxB1, XA.y, sdB);              \
        sdB = fmaf(wxB2, XB.x, sdB); sdB = fmaf(wxB3, XB.y, sdB);              \
        sdB = fmaf(wxB4, XC.x, sdB); sdB = fmaf(wxB5, XC.y, sdB);              \
        h2 hh[32];                                                             \
        hh[0]  = __builtin_bit_cast(h2, H0.x); hh[1]  = __builtin_bit_cast(h2, H0.y); \
        hh[2]  = __builtin_bit_cast(h2, H0.z); hh[3]  = __builtin_bit_cast(h2, H0.w); \
        hh[4]  = __builtin_bit_cast(h2, H1.x); hh[5]  = __builtin_bit_cast(h2, H1.y); \
        hh[6]  = __builtin_bit_cast(h2, H1.z); hh[7]  = __builtin_bit_cast(h2, H1.w); \
        hh[8]  = __builtin_bit_cast(h2, H2.x); hh[9]  = __builtin_bit_cast(h2, H2.y); \
        hh[10] = __builtin_bit_cast(h2, H2.z); hh[11] = __builtin_bit_cast(h2, H2.w); \
        hh[12] = __builtin_bit_cast(h2, H3.x); hh[13] = __builtin_bit_cast(h2, H3.y); \
        hh[14] = __builtin_bit_cast(h2, H3.z); hh[15] = __builtin_bit_cast(h2, H3.w); \
        hh[16] = __builtin_bit_cast(h2, H4.x); hh[17] = __builtin_bit_cast(h2, H4.y); \
        hh[18] = __builtin_bit_cast(h2, H4.z); hh[19] = __builtin_bit_cast(h2, H4.w); \
        hh[20] = __builtin_bit_cast(h2, H5.x); hh[21] = __builtin_bit_cast(h2, H5.y); \
        hh[22] = __builtin_bit_cast(h2, H5.z); hh[23] = __builtin_bit_cast(h2, H5.w); \
        hh[24] = __builtin_bit_cast(h2, H6.x); hh[25] = __builtin_bit_cast(h2, H6.y); \
        hh[26] = __builtin_bit_cast(h2, H6.z); hh[27] = __builtin_bit_cast(h2, H6.w); \
        hh[28] = __builtin_bit_cast(h2, H7.x); hh[29] = __builtin_bit_cast(h2, H7.y); \
        hh[30] = __builtin_bit_cast(h2, H7.z); hh[31] = __builtin_bit_cast(h2, H7.w); \
        float acc[4];                                                          \
        acc[0] = (q == 0) ? sdA : 0.0f;                                        \
        acc[1] = (q == 1) ? sdA : 0.0f;                                        \
        acc[2] = (q == 0) ? sdB : 0.0f;                                        \
        acc[3] = (q == 1) ? sdB : 0.0f;                                        \
        _Pragma("unroll")                                                      \
        for (int g = 0; g < 4; ++g) {                                          \
            float p = acc[g];                                                  \
            _Pragma("unroll")                                                  \
            for (int k = 0; k < 32; ++k)                                       \
                p = __builtin_amdgcn_fdot2(w[g][k], hh[k], p, false);          \
            acc[g] = p;                                                        \
        }                                                                      \
        _Pragma("unroll")                                                      \
        for (int g = 0; g < 4; ++g)                                            \
            acc[g] += dpp_f32<DPP_XOR1>(acc[g]);                               \
        const float ig = sigf(acc[0]);                                         \
        const float fg = sigf(acc[1]);                                         \
        const float gg = tanhfast(acc[2]);                                     \
        const float og = sigf(acc[3]);                                         \
        c  = fmaf(fg, c, ig * gg);                                             \
        hn = og * tanhfast(c);                                                 \
        if (q == 0) ((_Float16*)hbuf[BUF ^ 1])[j] = (_Float16)hn;              \
        __syncthreads();                                                       \
    }

    for (int t = 0; t < TS; t += 2) {
        DEC_STEP(0, sA, sB, sC);
        {
            const int tn = (t + 2 < TS) ? t + 2 : TS - 1;
            const float* p = sb + (size_t)tn * 6;
            sA = *(const float2*)(p);
            sB = *(const float2*)(p + 2);
            sC = *(const float2*)(p + 4);
        }
        DEC_STEP(1, sD, sE, sF);
        {
            const int tn = (t + 3 < TS) ? t + 3 : TS - 1;
            const float* p = sb + (size_t)tn * 6;
            sD = *(const float2*)(p);
            sE = *(const float2*)(p + 2);
            sF = *(const float2*)(p + 4);
        }
    }
#undef DEC_STEP

    if (q == 0) out_h[(size_t)b * DH + j] = hn;
}

extern "C" void kernel_launch(void* const* d_in, const int* in_sizes, int n_in,
                              void* d_out, int out_size, void* d_ws, size_t ws_size,
                              hipStream_t stream) {
    const float* x      = (const float*)d_in[0];
    const float* s      = (const float*)d_in[1];
    const float* h0     = (const float*)d_in[2];
    const float* c0     = (const float*)d_in[3];
    const float* We_ih  = (const float*)d_in[4];
    const float* We_hh  = (const float*)d_in[5];
    const float* be_ih  = (const float*)d_in[6];
    const float* be_hh  = (const float*)d_in[7];
    const float* Wfc_e  = (const float*)d_in[8];
    const float* bfc_e  = (const float*)d_in[9];
    const float* Wd_ih  = (const float*)d_in[10];
    const float* Wd_hh  = (const float*)d_in[11];
    const float* bd_ih  = (const float*)d_in[12];
    const float* bd_hh  = (const float*)d_in[13];
    const float* Wfc_d  = (const float*)d_in[14];
    const float* bfc_d  = (const float*)d_in[15];

    float* out      = (float*)d_out;
    float* out_z    = out;                           // [256]
    float* out_traj = out + BATCH;                   // [256*512*2]
    float* out_h    = out + BATCH + BATCH * TS * 2;  // [256*128]

    fused_kernel<<<BATCH, 256, 0, stream>>>(
        x, s, h0, c0, We_ih, We_hh, be_ih, be_hh, Wfc_e, bfc_e,
        Wd_ih, Wd_hh, bd_ih, bd_hh, Wfc_d, bfc_d,
        out_z, out_traj, out_h);
}